// Round 6
// baseline (930.620 us; speedup 1.0000x reference)
//
#include <hip/hip_runtime.h>
#include <type_traits>

typedef _Float16 f16;
typedef _Float16 f16x4 __attribute__((ext_vector_type(4)));
typedef _Float16 f16x8 __attribute__((ext_vector_type(8)));
typedef float    f32x4 __attribute__((ext_vector_type(4)));

constexpr int TT = 512;   // timesteps
constexpr int FF = 64;    // input features
constexpr int H1 = 128;   // layer-1 hidden (512 gate cols)
constexpr int H2 = 64;    // layer-2 hidden (256 gate cols)
constexpr int D1 = 25;    // dense-1 width
constexpr int S1 = 136;   // h1 LDS row stride (f16)
constexpr int S2 = 72;    // h2 LDS row stride
constexpr int XC = 8;     // x timesteps per staged LDS chunk
constexpr float L2E = 1.44269504088896f;

// R20: trans-free sigmoid. R14/R19 counters decompose the step as
// MFMA 1397 cy + TRANS 1152 cy (24 x 16cy wave64 exp/rcp x 3 waves) +
// main-VALU 210 cy ~= 2590 measured, and R19's static interleave of the
// trans bursts under MFMA chains recovered only 143 cy -> the trans unit
// serializes with the MFMA pipe regardless of scheduling. m114: plain
// FMA-class VALU DOES co-issue with MFMA across waves. So: compute
// sigma = 1/(1 + 2^-z) entirely on the main pipe: rndne range-reduce,
// 2^t Taylor deg-6 (|t|<=0.5, rel err ~1.2e-7), exponent via bit-assembly,
// rcp via bit-seed + 3 Newton (err ~1e-10). ~20 main-VALU ops, 0 trans.
__device__ __forceinline__ float sigm2(float z) {
    const float u = -z;                    // z pre-scaled by log2(e)
    const float n = __builtin_rintf(u);    // v_rndne_f32
    const float t = u - n;                 // |t| <= 0.5
    float p = 1.5402387e-4f;               // 2^t Taylor deg-6 (Horner)
    p = p * t + 1.3333558e-3f;
    p = p * t + 9.6181291e-3f;
    p = p * t + 5.5504109e-2f;
    p = p * t + 2.4022651e-1f;
    p = p * t + 6.9314718e-1f;
    p = p * t + 1.0f;
    const int ni = (int)n;                                  // integral, exact
    const float sc = __int_as_float((ni + 127) << 23);      // 2^n
    const float d = 1.0f + p * sc;                          // 1 + 2^-z
    float y = __int_as_float(0x7EF311C3 - __float_as_int(d));  // ~1/d seed
    y = y * (2.0f - d * y);                // Newton 1
    y = y * (2.0f - d * y);                // Newton 2
    y = y * (2.0f - d * y);                // Newton 3
    return y;
}

__device__ __forceinline__ f32x4 mfma16(f16x8 a, f16x8 b, f32x4 c) {
    return __builtin_amdgcn_mfma_f32_16x16x32_f16(a, b, c, 0, 0, 0);
}

__device__ __forceinline__ void gl_lds16(const f16* g, f16* l) {
    __builtin_amdgcn_global_load_lds(
        (const __attribute__((address_space(1))) unsigned int*)g,
        (__attribute__((address_space(3))) unsigned int*)l, 16, 0, 0);
}

// sched_group_barrier masks (LLVM SchedGroupMask): VALU=0x2 MFMA=0x8
// DS_READ=0x100 DS_WRITE=0x200
#define SGB __builtin_amdgcn_sched_group_barrier

// pre-pass: x fp32 -> f16 so staging is a raw byte copy.
__global__ void cvt_x_kernel(const float* __restrict__ x, f16* __restrict__ xh) {
    const size_t i = ((size_t)blockIdx.x * blockDim.x + threadIdx.x) * 4;
    const float4 v = *(const float4*)(x + i);
    f16x4 h; h[0] = (f16)v.x; h[1] = (f16)v.y; h[2] = (f16)v.z; h[3] = (f16)v.w;
    *(f16x4*)(xh + i) = h;
}

// Structure = R19 (552 us): 32 blocks x 768 threads (12 waves, 3/SIMD).
// Waves 0-7: layer-1 step i. Waves 8-11: layer-2 step i-1. Ping-pong h1/h2
// LDS => ONE barrier per step; gate-staged epilogue interleave pinned with
// SGB; x double-buffered via global_load_lds every 8 steps; s_setprio 1 on
// the L1 waves. ONLY change vs R19: sigm2 is trans-free (above) and SGB
// VALU group sizes updated for the larger main-pipe sigmoid bodies.
__global__ __launch_bounds__(768, 3)
void lstm_pipe12(const f16* __restrict__ xh, const float* __restrict__ W1,
                 const float* __restrict__ U1, const float* __restrict__ b1,
                 const float* __restrict__ W2, const float* __restrict__ U2,
                 const float* __restrict__ b2, const float* __restrict__ Wd1,
                 const float* __restrict__ bd1,const float* __restrict__ Wd2,
                 const float* __restrict__ bd2, float* __restrict__ out)
{
    const int tid  = threadIdx.x;
    const int w    = tid >> 6;      // wave 0..11
    const int lane = tid & 63;
    const int quad = lane >> 4;
    const int lid  = lane & 15;
    const int b0   = blockIdx.x * 16;
    const bool isL1 = (w < 8);
    const int  j    = isL1 ? w : (w - 8);

    __shared__ __align__(16) f16 h1b[2][16][S1];
    __shared__ __align__(16) f16 h2b[2][16][S2];
    // x chunk layout: [tl(8)][fseg(8)][row(16)] of 8-f16 (16 B) segments.
    __shared__ __align__(16) f16 xlds[2][XC * 8 * 16 * 8];
    __shared__ float h2f[16][H2];
    __shared__ float dsh[16][D1];

    for (int i = tid; i < 2 * 16 * S1 / 2; i += 768) ((unsigned*)h1b)[i] = 0u;
    for (int i = tid; i < 2 * 16 * S2 / 2; i += 768) ((unsigned*)h2b)[i] = 0u;

    // stage x chunk 0 (timesteps 0..7) into xlds[0]
    for (int s = tid; s < XC * 8 * 16; s += 768) {
        const int tl = s >> 7, fs = (s >> 4) & 7, row = s & 15;
        const f16* gp = xh + ((size_t)(b0 + row) * TT + tl) * FF + fs * 8;
        gl_lds16(gp, &xlds[0][(s >> 6) * 512]);
    }

    // ---- weight fragments wt[g][c] (A operand): lane holds col n=base+lid,
    // rows k = 32c + quad*8 + e. gates 0,1,3 (i,f,o) pre-scaled by log2e.
    // L1 (w<8):  chunks 0..3 = U1 (h1, K=128), 4..5 = W1 (x, K=64)
    // L2 (w>=8): chunks 0..3 = W2 (h1, K=128), 4..5 = U2 (h2, K=64)
    f16x8 wt[4][6];
    f32x4 bsp[4];     // bias for this lane's 4 consecutive gate cols (C-init)
    float cs[4] = {0.f, 0.f, 0.f, 0.f};

    if (isL1) {
#pragma unroll
        for (int g = 0; g < 4; ++g) {
            const float sc = (g == 2) ? 1.f : L2E;
            const int n = 128 * g + 16 * w + lid;
#pragma unroll
            for (int rr = 0; rr < 4; ++rr)
                bsp[g][rr] = b1[128 * g + 16 * w + quad * 4 + rr] * sc;
#pragma unroll
            for (int c = 0; c < 4; ++c) {
                f16x8 f;
#pragma unroll
                for (int e = 0; e < 8; ++e)
                    f[e] = (f16)(U1[(32 * c + quad * 8 + e) * 512 + n] * sc);
                wt[g][c] = f;
            }
#pragma unroll
            for (int c = 0; c < 2; ++c) {
                f16x8 f;
#pragma unroll
                for (int e = 0; e < 8; ++e)
                    f[e] = (f16)(W1[(32 * c + quad * 8 + e) * 512 + n] * sc);
                wt[g][4 + c] = f;
            }
        }
    } else {
#pragma unroll
        for (int g = 0; g < 4; ++g) {
            const float sc = (g == 2) ? 1.f : L2E;
            const int n = 64 * g + 16 * j + lid;
#pragma unroll
            for (int rr = 0; rr < 4; ++rr)
                bsp[g][rr] = b2[64 * g + 16 * j + quad * 4 + rr] * sc;
#pragma unroll
            for (int c = 0; c < 4; ++c) {
                f16x8 f;
#pragma unroll
                for (int e = 0; e < 8; ++e)
                    f[e] = (f16)(W2[(32 * c + quad * 8 + e) * 256 + n] * sc);
                wt[g][c] = f;
            }
#pragma unroll
            for (int c = 0; c < 2; ++c) {
                f16x8 f;
#pragma unroll
                for (int e = 0; e < 8; ++e)
                    f[e] = (f16)(U2[(32 * c + quad * 8 + e) * 256 + n] * sc);
                wt[g][4 + c] = f;
            }
        }
    }
    __syncthreads();   // also drains chunk-0 staging vmcnt

    // bias issue arbitration toward the serial L1 recurrence
    if (isL1) asm volatile("s_setprio 1");

    // one pipeline step; PAR = i&1 known at compile time => LDS immediates.
    // D[m=quad*4+r][n=lid]: m = 4 consecutive gate cols, n = batch row.
    auto step = [&](auto parc, int i) {
        constexpr int PAR = decltype(parc)::value;
        constexpr int PR = PAR ^ 1;   // h1[i-1]
        constexpr int PW = PAR;       // h1[i]
        constexpr int QR = PAR;       // h2[i-2]
        constexpr int QW = PAR ^ 1;   // h2[i-1]
        if (isL1) {
            const f16* xc = &xlds[(i >> 3) & 1][(i & 7) * 1024];
            f16x8 fr0 = *(const f16x8*)&h1b[PR][lid][quad * 8];
            f16x8 fr1 = *(const f16x8*)&h1b[PR][lid][32 + quad * 8];
            f16x8 fr2 = *(const f16x8*)&h1b[PR][lid][64 + quad * 8];
            f16x8 fr3 = *(const f16x8*)&h1b[PR][lid][96 + quad * 8];
            f16x8 xf0 = *(const f16x8*)&xc[(quad * 16 + lid) * 8];
            f16x8 xf1 = *(const f16x8*)&xc[((4 + quad) * 16 + lid) * 8];
            // gate 0 chain
            f32x4 a0 = mfma16(wt[0][0], fr0, bsp[0]);
            a0 = mfma16(wt[0][1], fr1, a0);
            a0 = mfma16(wt[0][2], fr2, a0);
            a0 = mfma16(wt[0][3], fr3, a0);
            a0 = mfma16(wt[0][4], xf0, a0);
            a0 = mfma16(wt[0][5], xf1, a0);
            // gate 1 chain
            f32x4 a1 = mfma16(wt[1][0], fr0, bsp[1]);
            a1 = mfma16(wt[1][1], fr1, a1);
            a1 = mfma16(wt[1][2], fr2, a1);
            a1 = mfma16(wt[1][3], fr3, a1);
            a1 = mfma16(wt[1][4], xf0, a1);
            a1 = mfma16(wt[1][5], xf1, a1);
            // sigma(gate0) -- overlaps gate1/2 MFMAs
            float ig[4];
#pragma unroll
            for (int r = 0; r < 4; ++r) ig[r] = sigm2(a0[r]);
            // gate 2 chain
            f32x4 a2 = mfma16(wt[2][0], fr0, bsp[2]);
            a2 = mfma16(wt[2][1], fr1, a2);
            a2 = mfma16(wt[2][2], fr2, a2);
            a2 = mfma16(wt[2][3], fr3, a2);
            a2 = mfma16(wt[2][4], xf0, a2);
            a2 = mfma16(wt[2][5], xf1, a2);
            // sigma(gate1)
            float fg[4];
#pragma unroll
            for (int r = 0; r < 4; ++r) fg[r] = sigm2(a1[r]);
            // gate 3 chain
            f32x4 a3 = mfma16(wt[3][0], fr0, bsp[3]);
            a3 = mfma16(wt[3][1], fr1, a3);
            a3 = mfma16(wt[3][2], fr2, a3);
            a3 = mfma16(wt[3][3], fr3, a3);
            a3 = mfma16(wt[3][4], xf0, a3);
            a3 = mfma16(wt[3][5], xf1, a3);
            // relu(gate2), sigma(gate3), combine
            f16x4 hp;
#pragma unroll
            for (int r = 0; r < 4; ++r) {
                const float gg = fmaxf(a2[r], 0.f);
                const float og = sigm2(a3[r]);
                const float cc = fg[r] * cs[r] + ig[r] * gg;
                cs[r] = cc;
                hp[r] = (f16)(og * fmaxf(cc, 0.f));
            }
            *(f16x4*)&h1b[PW][lid][16 * w + quad * 4] = hp;   // packed b64
            // scheduling recipe: reads first, then MFMA/VALU interleave
            SGB(0x100, 6, 0);   // 6 ds_read (fr0-3, xf0-1)
            SGB(0x008, 6, 0);   // gate0 MFMA
            SGB(0x008, 6, 0);   // gate1 MFMA
            SGB(0x002, 80, 0);  // sigma(gate0), main-pipe
            SGB(0x008, 6, 0);   // gate2 MFMA
            SGB(0x002, 80, 0);  // sigma(gate1)
            SGB(0x008, 6, 0);   // gate3 MFMA
            SGB(0x002, 100, 0); // relu + sigma(gate3) + combine head
        } else {
            if (i >= 1) {
                f16x8 fr0 = *(const f16x8*)&h1b[PR][lid][quad * 8];
                f16x8 fr1 = *(const f16x8*)&h1b[PR][lid][32 + quad * 8];
                f16x8 fr2 = *(const f16x8*)&h1b[PR][lid][64 + quad * 8];
                f16x8 fr3 = *(const f16x8*)&h1b[PR][lid][96 + quad * 8];
                f16x8 fr4 = *(const f16x8*)&h2b[QR][lid][quad * 8];
                f16x8 fr5 = *(const f16x8*)&h2b[QR][lid][32 + quad * 8];
                // gate 0 chain
                f32x4 a0 = mfma16(wt[0][0], fr0, bsp[0]);
                a0 = mfma16(wt[0][1], fr1, a0);
                a0 = mfma16(wt[0][2], fr2, a0);
                a0 = mfma16(wt[0][3], fr3, a0);
                a0 = mfma16(wt[0][4], fr4, a0);
                a0 = mfma16(wt[0][5], fr5, a0);
                // gate 1 chain
                f32x4 a1 = mfma16(wt[1][0], fr0, bsp[1]);
                a1 = mfma16(wt[1][1], fr1, a1);
                a1 = mfma16(wt[1][2], fr2, a1);
                a1 = mfma16(wt[1][3], fr3, a1);
                a1 = mfma16(wt[1][4], fr4, a1);
                a1 = mfma16(wt[1][5], fr5, a1);
                // sigma(gate0)
                float ig[4];
#pragma unroll
                for (int r = 0; r < 4; ++r) ig[r] = sigm2(a0[r]);
                // gate 2 chain
                f32x4 a2 = mfma16(wt[2][0], fr0, bsp[2]);
                a2 = mfma16(wt[2][1], fr1, a2);
                a2 = mfma16(wt[2][2], fr2, a2);
                a2 = mfma16(wt[2][3], fr3, a2);
                a2 = mfma16(wt[2][4], fr4, a2);
                a2 = mfma16(wt[2][5], fr5, a2);
                // sigma(gate1)
                float fg[4];
#pragma unroll
                for (int r = 0; r < 4; ++r) fg[r] = sigm2(a1[r]);
                // gate 3 chain
                f32x4 a3 = mfma16(wt[3][0], fr0, bsp[3]);
                a3 = mfma16(wt[3][1], fr1, a3);
                a3 = mfma16(wt[3][2], fr2, a3);
                a3 = mfma16(wt[3][3], fr3, a3);
                a3 = mfma16(wt[3][4], fr4, a3);
                a3 = mfma16(wt[3][5], fr5, a3);
                // relu(gate2), sigma(gate3), combine
                f16x4 hp;
#pragma unroll
                for (int r = 0; r < 4; ++r) {
                    const float gg = fmaxf(a2[r], 0.f);
                    const float og = sigm2(a3[r]);
                    const float cc = fg[r] * cs[r] + ig[r] * gg;
                    cs[r] = cc;
                    hp[r] = (f16)(og * fmaxf(cc, 0.f));
                }
                *(f16x4*)&h2b[QW][lid][16 * j + quad * 4] = hp;   // packed b64
                SGB(0x100, 6, 0);   // 6 ds_read
                SGB(0x008, 6, 0);   // gate0 MFMA
                SGB(0x008, 6, 0);   // gate1 MFMA
                SGB(0x002, 80, 0);  // sigma(gate0)
                SGB(0x008, 6, 0);   // gate2 MFMA
                SGB(0x002, 80, 0);  // sigma(gate1)
                SGB(0x008, 6, 0);   // gate3 MFMA
                SGB(0x002, 100, 0); // relu + sigma(gate3) + combine head
            }
        }
    };

    // ---------------- main loop, unrolled x2: ONE barrier per step ----------------
    for (int ii = 0; ii < TT; ii += 2) {
        if ((ii & (XC - 1)) == 0 && ii + XC < TT) {
            const int nc = (ii >> 3) + 1;
            f16* dst = xlds[nc & 1];
            for (int s = tid; s < XC * 8 * 16; s += 768) {
                const int tl = s >> 7, fs = (s >> 4) & 7, row = s & 15;
                const f16* gp = xh + ((size_t)(b0 + row) * TT + (nc * XC + tl)) * FF + fs * 8;
                gl_lds16(gp, &dst[(s >> 6) * 512]);
            }
        }
        step(std::integral_constant<int, 0>{}, ii);
        __syncthreads();
        step(std::integral_constant<int, 1>{}, ii + 1);
        __syncthreads();
    }

    if (isL1) asm volatile("s_setprio 0");

    // final pipeline step i=TT (even): L2 consumes h1[TT-1], exports h2 f32
    if (!isL1) {
        f16x8 fr0 = *(const f16x8*)&h1b[1][lid][quad * 8];
        f16x8 fr1 = *(const f16x8*)&h1b[1][lid][32 + quad * 8];
        f16x8 fr2 = *(const f16x8*)&h1b[1][lid][64 + quad * 8];
        f16x8 fr3 = *(const f16x8*)&h1b[1][lid][96 + quad * 8];
        f16x8 fr4 = *(const f16x8*)&h2b[0][lid][quad * 8];
        f16x8 fr5 = *(const f16x8*)&h2b[0][lid][32 + quad * 8];
        f32x4 acc[4];
#pragma unroll
        for (int g = 0; g < 4; ++g) {
            f32x4 a = mfma16(wt[g][0], fr0, bsp[g]);
            a = mfma16(wt[g][1], fr1, a);
            a = mfma16(wt[g][2], fr2, a);
            a = mfma16(wt[g][3], fr3, a);
            a = mfma16(wt[g][4], fr4, a);
            a = mfma16(wt[g][5], fr5, a);
            acc[g] = a;
        }
        float4 ho;
#pragma unroll
        for (int r = 0; r < 4; ++r) {
            const float ig = sigm2(acc[0][r]);
            const float fg = sigm2(acc[1][r]);
            const float gg = fmaxf(acc[2][r], 0.f);
            const float og = sigm2(acc[3][r]);
            const float cc = fg * cs[r] + ig * gg;
            (&ho.x)[r] = og * fmaxf(cc, 0.f);
        }
        *(float4*)&h2f[lid][16 * j + quad * 4] = ho;   // [batch][unit]
    }
    __syncthreads();

    // ---------------- dense head ----------------
    for (int idx = tid; idx < 16 * D1; idx += 768) {
        const int bq = idx / D1, p = idx % D1;
        float d = bd1[p];
#pragma unroll
        for (int k = 0; k < H2; ++k) d += h2f[bq][k] * Wd1[k * D1 + p];
        dsh[bq][p] = d * Wd2[p];
    }
    __syncthreads();
    if (tid < 16) {
        float o = bd2[0];
#pragma unroll
        for (int p = 0; p < D1; ++p) o += dsh[tid][p];
        out[b0 + tid] = o;
    }
}

extern "C" void kernel_launch(void* const* d_in, const int* in_sizes, int n_in,
                              void* d_out, int out_size, void* d_ws, size_t ws_size,
                              hipStream_t stream) {
    (void)in_sizes; (void)n_in; (void)out_size; (void)ws_size;
    const float* x   = (const float*)d_in[0];
    const float* W1  = (const float*)d_in[1];
    const float* U1  = (const float*)d_in[2];
    const float* b1  = (const float*)d_in[3];
    const float* W2  = (const float*)d_in[4];
    const float* U2  = (const float*)d_in[5];
    const float* b2  = (const float*)d_in[6];
    const float* Wd1 = (const float*)d_in[7];
    const float* bd1 = (const float*)d_in[8];
    const float* Wd2 = (const float*)d_in[9];
    const float* bd2 = (const float*)d_in[10];
    float* out = (float*)d_out;
    f16*   xh  = (f16*)d_ws;    // 512*512*64 f16 = 32 MiB scratch

    const int nx = 512 * 512 * 64;
    cvt_x_kernel<<<dim3(nx / (256 * 4)), dim3(256), 0, stream>>>(x, xh);
    lstm_pipe12<<<dim3(32), dim3(768), 0, stream>>>(
        xh, W1, U1, b1, W2, U2, b2, Wd1, bd1, Wd2, bd2, out);
}

// Round 7
// 668.062 us; speedup vs baseline: 1.3930x; 1.3930x over previous
//
#include <hip/hip_runtime.h>
#include <type_traits>

typedef _Float16 f16;
typedef _Float16 f16x4 __attribute__((ext_vector_type(4)));
typedef _Float16 f16x8 __attribute__((ext_vector_type(8)));
typedef float    f32x4 __attribute__((ext_vector_type(4)));

constexpr int TT = 512;   // timesteps
constexpr int FF = 64;    // input features
constexpr int H1 = 128;   // layer-1 hidden (512 gate cols)
constexpr int H2 = 64;    // layer-2 hidden (256 gate cols)
constexpr int D1 = 25;    // dense-1 width
constexpr int S1 = 136;   // h1 LDS row stride (f16)
constexpr int S2 = 72;    // h2 LDS row stride
constexpr int XC = 8;     // x timesteps per staged LDS chunk
constexpr float L2E = 1.44269504088896f;

// z pre-scaled by log2(e) at weight-load time: sigmoid = rcp(1 + 2^-z).
// (R20 lesson: trans ops are CHEAP on gfx950 -- replacing exp2+rcp with ~20
// main-pipe ops cost +900 VALU cy/step. Keep the 3-op trans form.)
__device__ __forceinline__ float sigm2(float z) {
    return __builtin_amdgcn_rcpf(1.f + __builtin_amdgcn_exp2f(-z));
}

__device__ __forceinline__ f32x4 mfma16(f16x8 a, f16x8 b, f32x4 c) {
    return __builtin_amdgcn_mfma_f32_16x16x32_f16(a, b, c, 0, 0, 0);
}

__device__ __forceinline__ void gl_lds16(const f16* g, f16* l) {
    __builtin_amdgcn_global_load_lds(
        (const __attribute__((address_space(1))) unsigned int*)g,
        (__attribute__((address_space(3))) unsigned int*)l, 16, 0, 0);
}

// sched_group_barrier masks (LLVM SchedGroupMask): VALU=0x2 MFMA=0x8
// DS_READ=0x100 DS_WRITE=0x200
#define SGB __builtin_amdgcn_sched_group_barrier

// pre-pass: x fp32 -> f16 so staging is a raw byte copy.
__global__ void cvt_x_kernel(const float* __restrict__ x, f16* __restrict__ xh) {
    const size_t i = ((size_t)blockIdx.x * blockDim.x + threadIdx.x) * 4;
    const float4 v = *(const float4*)(x + i);
    f16x4 h; h[0] = (f16)v.x; h[1] = (f16)v.y; h[2] = (f16)v.z; h[3] = (f16)v.w;
    *(f16x4*)(xh + i) = h;
}

// R21 = R19 (552 us, best) + per-wave PRIORITY STAGGER.
// Model: step = MFMA 1400 cy + VALU 1350 cy, ADDITIVE, because the 3
// barrier-locked waves per SIMD get round-robin matrix-pipe arbitration ->
// all finish MFMAs together, then all run epilogue VALU together. One wave
// alone saturates the matrix pipe (4 independent gate chains), so FIFO-by-
// wave would overlap: wave A's epilogue runs under wave B's MFMA burst.
// Waves map to SIMD by w%4 => {w, w+4, w+8} share a SIMD. Static prios
// 2/1/0 for waves 0-3 / 4-7 / 8-11 give each SIMD one wave per level and
// keep L1 above L2 (R14's bias). Math bit-identical to R19.
// Structure: 32 blocks x 768 threads. Waves 0-7: layer-1 step i. Waves 8-11:
// layer-2 step i-1. Ping-pong h1/h2 LDS => ONE barrier per step; gate-staged
// epilogue interleave pinned with SGB; x double-buffered via global_load_lds
// every 8 steps.
__global__ __launch_bounds__(768, 3)
void lstm_pipe12(const f16* __restrict__ xh, const float* __restrict__ W1,
                 const float* __restrict__ U1, const float* __restrict__ b1,
                 const float* __restrict__ W2, const float* __restrict__ U2,
                 const float* __restrict__ b2, const float* __restrict__ Wd1,
                 const float* __restrict__ bd1,const float* __restrict__ Wd2,
                 const float* __restrict__ bd2, float* __restrict__ out)
{
    const int tid  = threadIdx.x;
    const int w    = tid >> 6;      // wave 0..11
    const int lane = tid & 63;
    const int quad = lane >> 4;
    const int lid  = lane & 15;
    const int b0   = blockIdx.x * 16;
    const bool isL1 = (w < 8);
    const int  j    = isL1 ? w : (w - 8);

    __shared__ __align__(16) f16 h1b[2][16][S1];
    __shared__ __align__(16) f16 h2b[2][16][S2];
    // x chunk layout: [tl(8)][fseg(8)][row(16)] of 8-f16 (16 B) segments.
    __shared__ __align__(16) f16 xlds[2][XC * 8 * 16 * 8];
    __shared__ float h2f[16][H2];
    __shared__ float dsh[16][D1];

    for (int i = tid; i < 2 * 16 * S1 / 2; i += 768) ((unsigned*)h1b)[i] = 0u;
    for (int i = tid; i < 2 * 16 * S2 / 2; i += 768) ((unsigned*)h2b)[i] = 0u;

    // stage x chunk 0 (timesteps 0..7) into xlds[0]
    for (int s = tid; s < XC * 8 * 16; s += 768) {
        const int tl = s >> 7, fs = (s >> 4) & 7, row = s & 15;
        const f16* gp = xh + ((size_t)(b0 + row) * TT + tl) * FF + fs * 8;
        gl_lds16(gp, &xlds[0][(s >> 6) * 512]);
    }

    // ---- weight fragments wt[g][c] (A operand): lane holds col n=base+lid,
    // rows k = 32c + quad*8 + e. gates 0,1,3 (i,f,o) pre-scaled by log2e.
    // L1 (w<8):  chunks 0..3 = U1 (h1, K=128), 4..5 = W1 (x, K=64)
    // L2 (w>=8): chunks 0..3 = W2 (h1, K=128), 4..5 = U2 (h2, K=64)
    f16x8 wt[4][6];
    f32x4 bsp[4];     // bias for this lane's 4 consecutive gate cols (C-init)
    float cs[4] = {0.f, 0.f, 0.f, 0.f};

    if (isL1) {
#pragma unroll
        for (int g = 0; g < 4; ++g) {
            const float sc = (g == 2) ? 1.f : L2E;
            const int n = 128 * g + 16 * w + lid;
#pragma unroll
            for (int rr = 0; rr < 4; ++rr)
                bsp[g][rr] = b1[128 * g + 16 * w + quad * 4 + rr] * sc;
#pragma unroll
            for (int c = 0; c < 4; ++c) {
                f16x8 f;
#pragma unroll
                for (int e = 0; e < 8; ++e)
                    f[e] = (f16)(U1[(32 * c + quad * 8 + e) * 512 + n] * sc);
                wt[g][c] = f;
            }
#pragma unroll
            for (int c = 0; c < 2; ++c) {
                f16x8 f;
#pragma unroll
                for (int e = 0; e < 8; ++e)
                    f[e] = (f16)(W1[(32 * c + quad * 8 + e) * 512 + n] * sc);
                wt[g][4 + c] = f;
            }
        }
    } else {
#pragma unroll
        for (int g = 0; g < 4; ++g) {
            const float sc = (g == 2) ? 1.f : L2E;
            const int n = 64 * g + 16 * j + lid;
#pragma unroll
            for (int rr = 0; rr < 4; ++rr)
                bsp[g][rr] = b2[64 * g + 16 * j + quad * 4 + rr] * sc;
#pragma unroll
            for (int c = 0; c < 4; ++c) {
                f16x8 f;
#pragma unroll
                for (int e = 0; e < 8; ++e)
                    f[e] = (f16)(W2[(32 * c + quad * 8 + e) * 256 + n] * sc);
                wt[g][c] = f;
            }
#pragma unroll
            for (int c = 0; c < 2; ++c) {
                f16x8 f;
#pragma unroll
                for (int e = 0; e < 8; ++e)
                    f[e] = (f16)(U2[(32 * c + quad * 8 + e) * 256 + n] * sc);
                wt[g][4 + c] = f;
            }
        }
    }
    __syncthreads();   // also drains chunk-0 staging vmcnt

    // priority stagger: one wave per level per SIMD (SIMD = w%4).
    // waves 0-3: prio 2, waves 4-7: prio 1, waves 8-11 (L2): prio 0.
    if (w < 4)      asm volatile("s_setprio 2");
    else if (w < 8) asm volatile("s_setprio 1");

    // one pipeline step; PAR = i&1 known at compile time => LDS immediates.
    // D[m=quad*4+r][n=lid]: m = 4 consecutive gate cols, n = batch row.
    auto step = [&](auto parc, int i) {
        constexpr int PAR = decltype(parc)::value;
        constexpr int PR = PAR ^ 1;   // h1[i-1]
        constexpr int PW = PAR;       // h1[i]
        constexpr int QR = PAR;       // h2[i-2]
        constexpr int QW = PAR ^ 1;   // h2[i-1]
        if (isL1) {
            const f16* xc = &xlds[(i >> 3) & 1][(i & 7) * 1024];
            f16x8 fr0 = *(const f16x8*)&h1b[PR][lid][quad * 8];
            f16x8 fr1 = *(const f16x8*)&h1b[PR][lid][32 + quad * 8];
            f16x8 fr2 = *(const f16x8*)&h1b[PR][lid][64 + quad * 8];
            f16x8 fr3 = *(const f16x8*)&h1b[PR][lid][96 + quad * 8];
            f16x8 xf0 = *(const f16x8*)&xc[(quad * 16 + lid) * 8];
            f16x8 xf1 = *(const f16x8*)&xc[((4 + quad) * 16 + lid) * 8];
            // gate 0 chain
            f32x4 a0 = mfma16(wt[0][0], fr0, bsp[0]);
            a0 = mfma16(wt[0][1], fr1, a0);
            a0 = mfma16(wt[0][2], fr2, a0);
            a0 = mfma16(wt[0][3], fr3, a0);
            a0 = mfma16(wt[0][4], xf0, a0);
            a0 = mfma16(wt[0][5], xf1, a0);
            // gate 1 chain
            f32x4 a1 = mfma16(wt[1][0], fr0, bsp[1]);
            a1 = mfma16(wt[1][1], fr1, a1);
            a1 = mfma16(wt[1][2], fr2, a1);
            a1 = mfma16(wt[1][3], fr3, a1);
            a1 = mfma16(wt[1][4], xf0, a1);
            a1 = mfma16(wt[1][5], xf1, a1);
            // sigma(gate0) -- overlaps gate1/2 MFMAs
            float ig[4];
#pragma unroll
            for (int r = 0; r < 4; ++r) ig[r] = sigm2(a0[r]);
            // gate 2 chain
            f32x4 a2 = mfma16(wt[2][0], fr0, bsp[2]);
            a2 = mfma16(wt[2][1], fr1, a2);
            a2 = mfma16(wt[2][2], fr2, a2);
            a2 = mfma16(wt[2][3], fr3, a2);
            a2 = mfma16(wt[2][4], xf0, a2);
            a2 = mfma16(wt[2][5], xf1, a2);
            // sigma(gate1)
            float fg[4];
#pragma unroll
            for (int r = 0; r < 4; ++r) fg[r] = sigm2(a1[r]);
            // gate 3 chain
            f32x4 a3 = mfma16(wt[3][0], fr0, bsp[3]);
            a3 = mfma16(wt[3][1], fr1, a3);
            a3 = mfma16(wt[3][2], fr2, a3);
            a3 = mfma16(wt[3][3], fr3, a3);
            a3 = mfma16(wt[3][4], xf0, a3);
            a3 = mfma16(wt[3][5], xf1, a3);
            // relu(gate2), sigma(gate3), combine
            f16x4 hp;
#pragma unroll
            for (int r = 0; r < 4; ++r) {
                const float gg = fmaxf(a2[r], 0.f);
                const float og = sigm2(a3[r]);
                const float cc = fg[r] * cs[r] + ig[r] * gg;
                cs[r] = cc;
                hp[r] = (f16)(og * fmaxf(cc, 0.f));
            }
            *(f16x4*)&h1b[PW][lid][16 * w + quad * 4] = hp;   // packed b64
            // scheduling recipe: reads first, then MFMA/VALU interleave
            SGB(0x100, 6, 0);   // 6 ds_read (fr0-3, xf0-1)
            SGB(0x008, 6, 0);   // gate0 MFMA
            SGB(0x008, 6, 0);   // gate1 MFMA
            SGB(0x002, 12, 0);  // sigma(gate0)
            SGB(0x008, 6, 0);   // gate2 MFMA
            SGB(0x002, 12, 0);  // sigma(gate1)
            SGB(0x008, 6, 0);   // gate3 MFMA
            SGB(0x002, 20, 0);  // relu + sigma(gate3) + combine head
        } else {
            if (i >= 1) {
                f16x8 fr0 = *(const f16x8*)&h1b[PR][lid][quad * 8];
                f16x8 fr1 = *(const f16x8*)&h1b[PR][lid][32 + quad * 8];
                f16x8 fr2 = *(const f16x8*)&h1b[PR][lid][64 + quad * 8];
                f16x8 fr3 = *(const f16x8*)&h1b[PR][lid][96 + quad * 8];
                f16x8 fr4 = *(const f16x8*)&h2b[QR][lid][quad * 8];
                f16x8 fr5 = *(const f16x8*)&h2b[QR][lid][32 + quad * 8];
                // gate 0 chain
                f32x4 a0 = mfma16(wt[0][0], fr0, bsp[0]);
                a0 = mfma16(wt[0][1], fr1, a0);
                a0 = mfma16(wt[0][2], fr2, a0);
                a0 = mfma16(wt[0][3], fr3, a0);
                a0 = mfma16(wt[0][4], fr4, a0);
                a0 = mfma16(wt[0][5], fr5, a0);
                // gate 1 chain
                f32x4 a1 = mfma16(wt[1][0], fr0, bsp[1]);
                a1 = mfma16(wt[1][1], fr1, a1);
                a1 = mfma16(wt[1][2], fr2, a1);
                a1 = mfma16(wt[1][3], fr3, a1);
                a1 = mfma16(wt[1][4], fr4, a1);
                a1 = mfma16(wt[1][5], fr5, a1);
                // sigma(gate0)
                float ig[4];
#pragma unroll
                for (int r = 0; r < 4; ++r) ig[r] = sigm2(a0[r]);
                // gate 2 chain
                f32x4 a2 = mfma16(wt[2][0], fr0, bsp[2]);
                a2 = mfma16(wt[2][1], fr1, a2);
                a2 = mfma16(wt[2][2], fr2, a2);
                a2 = mfma16(wt[2][3], fr3, a2);
                a2 = mfma16(wt[2][4], fr4, a2);
                a2 = mfma16(wt[2][5], fr5, a2);
                // sigma(gate1)
                float fg[4];
#pragma unroll
                for (int r = 0; r < 4; ++r) fg[r] = sigm2(a1[r]);
                // gate 3 chain
                f32x4 a3 = mfma16(wt[3][0], fr0, bsp[3]);
                a3 = mfma16(wt[3][1], fr1, a3);
                a3 = mfma16(wt[3][2], fr2, a3);
                a3 = mfma16(wt[3][3], fr3, a3);
                a3 = mfma16(wt[3][4], fr4, a3);
                a3 = mfma16(wt[3][5], fr5, a3);
                // relu(gate2), sigma(gate3), combine
                f16x4 hp;
#pragma unroll
                for (int r = 0; r < 4; ++r) {
                    const float gg = fmaxf(a2[r], 0.f);
                    const float og = sigm2(a3[r]);
                    const float cc = fg[r] * cs[r] + ig[r] * gg;
                    cs[r] = cc;
                    hp[r] = (f16)(og * fmaxf(cc, 0.f));
                }
                *(f16x4*)&h2b[QW][lid][16 * j + quad * 4] = hp;   // packed b64
                SGB(0x100, 6, 0);   // 6 ds_read
                SGB(0x008, 6, 0);   // gate0 MFMA
                SGB(0x008, 6, 0);   // gate1 MFMA
                SGB(0x002, 12, 0);  // sigma(gate0)
                SGB(0x008, 6, 0);   // gate2 MFMA
                SGB(0x002, 12, 0);  // sigma(gate1)
                SGB(0x008, 6, 0);   // gate3 MFMA
                SGB(0x002, 20, 0);  // relu + sigma(gate3) + combine head
            }
        }
    };

    // ---------------- main loop, unrolled x2: ONE barrier per step ----------------
    for (int ii = 0; ii < TT; ii += 2) {
        if ((ii & (XC - 1)) == 0 && ii + XC < TT) {
            const int nc = (ii >> 3) + 1;
            f16* dst = xlds[nc & 1];
            for (int s = tid; s < XC * 8 * 16; s += 768) {
                const int tl = s >> 7, fs = (s >> 4) & 7, row = s & 15;
                const f16* gp = xh + ((size_t)(b0 + row) * TT + (nc * XC + tl)) * FF + fs * 8;
                gl_lds16(gp, &dst[(s >> 6) * 512]);
            }
        }
        step(std::integral_constant<int, 0>{}, ii);
        __syncthreads();
        step(std::integral_constant<int, 1>{}, ii + 1);
        __syncthreads();
    }

    asm volatile("s_setprio 0");

    // final pipeline step i=TT (even): L2 consumes h1[TT-1], exports h2 f32
    if (!isL1) {
        f16x8 fr0 = *(const f16x8*)&h1b[1][lid][quad * 8];
        f16x8 fr1 = *(const f16x8*)&h1b[1][lid][32 + quad * 8];
        f16x8 fr2 = *(const f16x8*)&h1b[1][lid][64 + quad * 8];
        f16x8 fr3 = *(const f16x8*)&h1b[1][lid][96 + quad * 8];
        f16x8 fr4 = *(const f16x8*)&h2b[0][lid][quad * 8];
        f16x8 fr5 = *(const f16x8*)&h2b[0][lid][32 + quad * 8];
        f32x4 acc[4];
#pragma unroll
        for (int g = 0; g < 4; ++g) {
            f32x4 a = mfma16(wt[g][0], fr0, bsp[g]);
            a = mfma16(wt[g][1], fr1, a);
            a = mfma16(wt[g][2], fr2, a);
            a = mfma16(wt[g][3], fr3, a);
            a = mfma16(wt[g][4], fr4, a);
            a = mfma16(wt[g][5], fr5, a);
            acc[g] = a;
        }
        float4 ho;
#pragma unroll
        for (int r = 0; r < 4; ++r) {
            const float ig = sigm2(acc[0][r]);
            const float fg = sigm2(acc[1][r]);
            const float gg = fmaxf(acc[2][r], 0.f);
            const float og = sigm2(acc[3][r]);
            const float cc = fg * cs[r] + ig * gg;
            (&ho.x)[r] = og * fmaxf(cc, 0.f);
        }
        *(float4*)&h2f[lid][16 * j + quad * 4] = ho;   // [batch][unit]
    }
    __syncthreads();

    // ---------------- dense head ----------------
    for (int idx = tid; idx < 16 * D1; idx += 768) {
        const int bq = idx / D1, p = idx % D1;
        float d = bd1[p];
#pragma unroll
        for (int k = 0; k < H2; ++k) d += h2f[bq][k] * Wd1[k * D1 + p];
        dsh[bq][p] = d * Wd2[p];
    }
    __syncthreads();
    if (tid < 16) {
        float o = bd2[0];
#pragma unroll
        for (int p = 0; p < D1; ++p) o += dsh[tid][p];
        out[b0 + tid] = o;
    }
}

extern "C" void kernel_launch(void* const* d_in, const int* in_sizes, int n_in,
                              void* d_out, int out_size, void* d_ws, size_t ws_size,
                              hipStream_t stream) {
    (void)in_sizes; (void)n_in; (void)out_size; (void)ws_size;
    const float* x   = (const float*)d_in[0];
    const float* W1  = (const float*)d_in[1];
    const float* U1  = (const float*)d_in[2];
    const float* b1  = (const float*)d_in[3];
    const float* W2  = (const float*)d_in[4];
    const float* U2  = (const float*)d_in[5];
    const float* b2  = (const float*)d_in[6];
    const float* Wd1 = (const float*)d_in[7];
    const float* bd1 = (const float*)d_in[8];
    const float* Wd2 = (const float*)d_in[9];
    const float* bd2 = (const float*)d_in[10];
    float* out = (float*)d_out;
    f16*   xh  = (f16*)d_ws;    // 512*512*64 f16 = 32 MiB scratch

    const int nx = 512 * 512 * 64;
    cvt_x_kernel<<<dim3(nx / (256 * 4)), dim3(256), 0, stream>>>(x, xh);
    lstm_pipe12<<<dim3(32), dim3(768), 0, stream>>>(
        xh, W1, U1, b1, W2, U2, b2, Wd1, bd1, Wd2, bd2, out);
}